// Round 1
// baseline (760.920 us; speedup 1.0000x reference)
//
#include <hip/hip_runtime.h>
#include <math.h>

// ---------------------------------------------------------------------------
// GuardNet: 2-layer attention-weighted GCN.
//   layer: cos-sim on features -> threshold 0.1 -> L1 row-norm -> exp ->
//          sym-norm GCN with degree-based self loops -> (relu | log_softmax)
// Strategy: edge-parallel kernels with scalar atomics for segment sums of
// scalars; CSR built per-launch (counting sort by row) so the [N,F] feature
// aggregation is a pure gather (wave per node, lane per feature dim).
// ---------------------------------------------------------------------------

#define WAVE 64

// inverse L2 norm per node row (D=64). one wave per node.
__global__ void k_norm(const float* __restrict__ fea, float* __restrict__ invn, int n)
{
    int gid  = blockIdx.x * blockDim.x + threadIdx.x;
    int wid  = gid >> 6;
    int lane = threadIdx.x & 63;
    if (wid >= n) return;
    float v = fea[(size_t)wid * 64 + lane];
    float s = v * v;
#pragma unroll
    for (int off = 32; off > 0; off >>= 1) s += __shfl_xor(s, off);
    if (lane == 0) invn[wid] = 1.0f / fmaxf(sqrtf(s), 1e-12f);
}

// edge cosine similarity + threshold; accumulate rs (sum of kept sims) and
// degcnt (count of kept edges) per row. 8 lanes per edge, 8 floats per lane.
__global__ void k_sim(const float* __restrict__ fea, const float* __restrict__ invn,
                      const int* __restrict__ row, const int* __restrict__ col,
                      float* __restrict__ sim, float* __restrict__ rs,
                      float* __restrict__ degcnt, int E)
{
    int t = blockIdx.x * blockDim.x + threadIdx.x;
    int e = t >> 3;
    int sub = t & 7;
    if (e >= E) return;
    int r = row[e], c = col[e];
    const float4* fr = (const float4*)(fea + (size_t)r * 64);
    const float4* fc = (const float4*)(fea + (size_t)c * 64);
    float4 a0 = fr[sub * 2], a1 = fr[sub * 2 + 1];
    float4 b0 = fc[sub * 2], b1 = fc[sub * 2 + 1];
    float p = a0.x * b0.x + a0.y * b0.y + a0.z * b0.z + a0.w * b0.w
            + a1.x * b1.x + a1.y * b1.y + a1.z * b1.z + a1.w * b1.w;
    p += __shfl_xor(p, 1);
    p += __shfl_xor(p, 2);
    p += __shfl_xor(p, 4);
    if (sub == 0) {
        float s = p * invn[r] * invn[c];
        if (s < 0.1f) s = 0.0f;
        sim[e] = s;
        if (s > 0.0f) {
            atomicAdd(rs + r, s);
            atomicAdd(degcnt + r, 1.0f);
        }
    }
}

// per-edge: w = exp(sim / max(rs[row],1e-12)) for kept edges; segW[row] += w.
// simw is sim on input, w_edge on output (in place).
__global__ void k_wedge(const int* __restrict__ row, float* __restrict__ simw,
                        const float* __restrict__ rs, float* __restrict__ segW, int E)
{
    int e = blockIdx.x * blockDim.x + threadIdx.x;
    if (e >= E) return;
    float s = simw[e];
    float w = 0.0f;
    if (s > 0.0f) {
        int r = row[e];
        w = expf(s / fmaxf(rs[r], 1e-12f));
        atomicAdd(segW + r, w);
    }
    simw[e] = w;
}

// per-node: self-loop weight, dinv = 1/sqrt(deg), selfc = w_self*dinv*dinv
__global__ void k_node(const float* __restrict__ degcnt, const float* __restrict__ segW,
                       float* __restrict__ dinv, float* __restrict__ selfc, int n)
{
    int i = blockIdx.x * blockDim.x + threadIdx.x;
    if (i >= n) return;
    float ws  = expf(1.0f / (degcnt[i] + 1.0f));
    float deg = segW[i] + ws;
    float di  = rsqrtf(fmaxf(deg, 1e-12f));
    dinv[i]  = di;
    selfc[i] = ws * di * di;
}

// CSR build: count edges per row
__global__ void k_count(const int* __restrict__ row, int* __restrict__ cnt, int E)
{
    int e = blockIdx.x * blockDim.x + threadIdx.x;
    if (e >= E) return;
    atomicAdd(cnt + row[e], 1);
}

// exclusive prefix sum of cnt[0..n) -> row_ptr[0..n]. single block, 256 thr.
__global__ void k_scan(const int* __restrict__ cnt, int* __restrict__ row_ptr, int n)
{
    __shared__ int ssum[256];
    int tid = threadIdx.x;
    int chunk = (n + 255) / 256;
    int beg = tid * chunk;
    int end = beg + chunk; if (end > n) end = n; if (beg > n) beg = n;
    int s = 0;
    for (int i = beg; i < end; ++i) s += cnt[i];
    ssum[tid] = s;
    __syncthreads();
    if (tid == 0) {
        int acc = 0;
        for (int i = 0; i < 256; ++i) { int v = ssum[i]; ssum[i] = acc; acc += v; }
    }
    __syncthreads();
    int acc = ssum[tid];
    for (int i = beg; i < end; ++i) { row_ptr[i] = acc; acc += cnt[i]; }
    if (tid == 255) row_ptr[n] = acc;
}

// CSR fill: scatter (col, edge-id) into sorted-by-row position
__global__ void k_fill(const int* __restrict__ row, const int* __restrict__ col,
                       const int* __restrict__ row_ptr, int* __restrict__ cursor,
                       int* __restrict__ col_s, int* __restrict__ eid_s, int E)
{
    int e = blockIdx.x * blockDim.x + threadIdx.x;
    if (e >= E) return;
    int r = row[e];
    int pos = row_ptr[r] + atomicAdd(cursor + r, 1);
    col_s[pos] = col[e];
    eid_s[pos] = e;
}

// dense GEMM out[N,F] = fea[N,64] @ W[64,F].  W + row tile staged in LDS.
template <int F>
__global__ void k_gemm(const float* __restrict__ fea, const float* __restrict__ W,
                       float* __restrict__ out, int n)
{
    constexpr int R = 256 / F; // rows per block
    __shared__ float sW[64 * F];
    __shared__ float sX[R * 64];
    int tid = threadIdx.x;
    for (int i = tid; i < 64 * F; i += 256) sW[i] = W[i];
    int base = blockIdx.x * R;
    for (int i = tid; i < R * 64; i += 256) {
        int rr = base + i / 64;
        sX[i] = (rr < n) ? fea[(size_t)rr * 64 + (i & 63)] : 0.0f;
    }
    __syncthreads();
    int rl = tid / F, j = tid % F;
    if (rl >= R) return;
    int r = base + rl;
    if (r >= n) return;
    float acc = 0.0f;
#pragma unroll
    for (int k = 0; k < 64; ++k) acc = fmaf(sX[rl * 64 + k], sW[k * F + j], acc);
    out[(size_t)r * F + j] = acc;
}

// layer-1 aggregation: out = dinv[n]*sum_e(w_e*dinv[col]*h[col]) + selfc*h[n] + b,
// relu, and fused inverse-norm of the relu output (for layer-2 attention).
// one wave per node, lane = feature dim.
__global__ void k_agg64(const float* __restrict__ h, const float* __restrict__ w_edge,
                        const float* __restrict__ dinv, const float* __restrict__ selfc,
                        const float* __restrict__ b, const int* __restrict__ row_ptr,
                        const int* __restrict__ col_s, const int* __restrict__ eid_s,
                        float* __restrict__ out, float* __restrict__ invn_out, int n)
{
    int gid  = blockIdx.x * blockDim.x + threadIdx.x;
    int wid  = gid >> 6;
    int lane = threadIdx.x & 63;
    if (wid >= n) return;
    int beg = row_ptr[wid], end = row_ptr[wid + 1];
    float acc = 0.0f;
    for (int idx = beg; idx < end; ++idx) {
        int c = col_s[idx];
        int e = eid_s[idx];
        float w = w_edge[e];           // wave-uniform
        if (w > 0.0f) acc += w * dinv[c] * h[(size_t)c * 64 + lane];
    }
    float v = dinv[wid] * acc + selfc[wid] * h[(size_t)wid * 64 + lane] + b[lane];
    v = fmaxf(v, 0.0f); // relu
    out[(size_t)wid * 64 + lane] = v;
    float s = v * v;
#pragma unroll
    for (int off = 32; off > 0; off >>= 1) s += __shfl_xor(s, off);
    if (lane == 0) invn_out[wid] = 1.0f / fmaxf(sqrtf(s), 1e-12f);
}

// layer-2 aggregation (F=40) fused with bias + log_softmax -> final output.
__global__ void k_agg40_lsm(const float* __restrict__ h2, const float* __restrict__ w_edge,
                            const float* __restrict__ dinv, const float* __restrict__ selfc,
                            const float* __restrict__ b, const int* __restrict__ row_ptr,
                            const int* __restrict__ col_s, const int* __restrict__ eid_s,
                            float* __restrict__ out, int n, int F)
{
    int gid  = blockIdx.x * blockDim.x + threadIdx.x;
    int wid  = gid >> 6;
    int lane = threadIdx.x & 63;
    if (wid >= n) return;
    int beg = row_ptr[wid], end = row_ptr[wid + 1];
    float acc = 0.0f;
    bool active = (lane < F);
    for (int idx = beg; idx < end; ++idx) {
        int c = col_s[idx];
        int e = eid_s[idx];
        float w = w_edge[e];           // wave-uniform
        if (w > 0.0f && active) acc += w * dinv[c] * h2[(size_t)c * F + lane];
    }
    float v = 0.0f;
    if (active) v = dinv[wid] * acc + selfc[wid] * h2[(size_t)wid * F + lane] + b[lane];
    // log_softmax over F classes (64-lane shuffle reductions)
    float m = active ? v : -__builtin_inff();
#pragma unroll
    for (int off = 32; off > 0; off >>= 1) m = fmaxf(m, __shfl_xor(m, off));
    float ex = active ? expf(v - m) : 0.0f;
    float s = ex;
#pragma unroll
    for (int off = 32; off > 0; off >>= 1) s += __shfl_xor(s, off);
    if (active) out[(size_t)wid * F + lane] = v - m - logf(s);
}

extern "C" void kernel_launch(void* const* d_in, const int* in_sizes, int n_in,
                              void* d_out, int out_size, void* d_ws, size_t ws_size,
                              hipStream_t stream)
{
    const float* x  = (const float*)d_in[0];
    const int*   ei = (const int*)d_in[1];
    const float* W1 = (const float*)d_in[2];
    const float* b1 = (const float*)d_in[3];
    const float* W2 = (const float*)d_in[4];
    const float* b2 = (const float*)d_in[5];
    float* out = (float*)d_out;

    const int N = in_sizes[0] / 64;   // 50000
    const int E = in_sizes[1] / 2;    // 800000
    const int NCLS = in_sizes[5];     // 40
    const int* row = ei;
    const int* col = ei + E;

    // ---- workspace carve (ws poisoned 0xAA each call: zero what we accumulate)
    char* p = (char*)d_ws;
    auto alloc = [&](size_t bytes) -> char* {
        char* r = p; p += (bytes + 255) & ~(size_t)255; return r;
    };
    float* invn_x = (float*)alloc((size_t)N * 4);
    float* invn_h = (float*)alloc((size_t)N * 4);
    float* simw   = (float*)alloc((size_t)E * 4);   // sim -> w_edge, reused per layer
    float* rs     = (float*)alloc((size_t)N * 4);
    float* degc   = (float*)alloc((size_t)N * 4);
    float* segW   = (float*)alloc((size_t)N * 4);
    float* dinv   = (float*)alloc((size_t)N * 4);
    float* selfc  = (float*)alloc((size_t)N * 4);
    float* h1     = (float*)alloc((size_t)N * 64 * 4); // x@W1; reused as h2 (N*40)
    float* hrelu  = (float*)alloc((size_t)N * 64 * 4); // relu output / layer-2 features
    int*   cnt    = (int*)alloc((size_t)N * 4);
    int*   cursor = (int*)alloc((size_t)N * 4);
    int*   rptr   = (int*)alloc((size_t)(N + 1) * 4);
    int*   col_s  = (int*)alloc((size_t)E * 4);
    int*   eid_s  = (int*)alloc((size_t)E * 4);
    float* h2     = h1;

    const int TB = 256;
    int blk_nodeWave = (N * 64 + TB - 1) / TB;   // one wave per node
    int blk_edge8    = (E * 8 + TB - 1) / TB;    // 8 lanes per edge
    int blk_edge     = (E + TB - 1) / TB;
    int blk_node     = (N + TB - 1) / TB;

    // ---- zero accumulators (layer 1 + CSR)
    hipMemsetAsync(rs,     0, (size_t)N * 4, stream);
    hipMemsetAsync(degc,   0, (size_t)N * 4, stream);
    hipMemsetAsync(segW,   0, (size_t)N * 4, stream);
    hipMemsetAsync(cnt,    0, (size_t)N * 4, stream);
    hipMemsetAsync(cursor, 0, (size_t)N * 4, stream);

    // ---- CSR build (row structure shared by both layers)
    k_count<<<blk_edge, TB, 0, stream>>>(row, cnt, E);
    k_scan<<<1, TB, 0, stream>>>(cnt, rptr, N);
    k_fill<<<blk_edge, TB, 0, stream>>>(row, col, rptr, cursor, col_s, eid_s, E);

    // ---- layer 1 attention
    k_norm<<<blk_nodeWave, TB, 0, stream>>>(x, invn_x, N);
    k_sim<<<blk_edge8, TB, 0, stream>>>(x, invn_x, row, col, simw, rs, degc, E);
    k_wedge<<<blk_edge, TB, 0, stream>>>(row, simw, rs, segW, E);
    k_node<<<blk_node, TB, 0, stream>>>(degc, segW, dinv, selfc, N);

    // ---- layer 1 GCN
    k_gemm<64><<<(N + 3) / 4, TB, 0, stream>>>(x, W1, h1, N);
    k_agg64<<<blk_nodeWave, TB, 0, stream>>>(h1, simw, dinv, selfc, b1,
                                             rptr, col_s, eid_s, hrelu, invn_h, N);

    // ---- layer 2 attention (on relu output)
    hipMemsetAsync(rs,   0, (size_t)N * 4, stream);
    hipMemsetAsync(degc, 0, (size_t)N * 4, stream);
    hipMemsetAsync(segW, 0, (size_t)N * 4, stream);
    k_sim<<<blk_edge8, TB, 0, stream>>>(hrelu, invn_h, row, col, simw, rs, degc, E);
    k_wedge<<<blk_edge, TB, 0, stream>>>(row, simw, rs, segW, E);
    k_node<<<blk_node, TB, 0, stream>>>(degc, segW, dinv, selfc, N);

    // ---- layer 2 GCN + log_softmax
    k_gemm<40><<<(N + 5) / 6, TB, 0, stream>>>(hrelu, W2, h2, N);
    k_agg40_lsm<<<blk_nodeWave, TB, 0, stream>>>(h2, simw, dinv, selfc, b2,
                                                 rptr, col_s, eid_s, out, N, NCLS);
}

// Round 2
// 542.110 us; speedup vs baseline: 1.4036x; 1.4036x over previous
//
#include <hip/hip_runtime.h>
#include <math.h>

// ---------------------------------------------------------------------------
// GuardNet: 2-layer attention-weighted GCN.
// R2: CSR-ordered weights (no eid indirection), coalesced (col,w) block loads,
// ballot-mask live-edge extraction with 4-way gather ILP, count fused into sim,
// 1024-thread shuffle scan.
// ---------------------------------------------------------------------------

// inverse L2 norm per node row (D=64). one wave per node.
__global__ void k_norm(const float* __restrict__ fea, float* __restrict__ invn, int n)
{
    int gid  = blockIdx.x * blockDim.x + threadIdx.x;
    int wid  = gid >> 6;
    int lane = threadIdx.x & 63;
    if (wid >= n) return;
    float v = fea[(size_t)wid * 64 + lane];
    float s = v * v;
#pragma unroll
    for (int off = 32; off > 0; off >>= 1) s += __shfl_xor(s, off);
    if (lane == 0) invn[wid] = 1.0f / fmaxf(sqrtf(s), 1e-12f);
}

// edge cosine similarity + threshold; accumulate rs (sum of kept sims) and
// degcnt (count of kept edges) per row; optionally CSR edge count (all edges).
// 8 lanes per edge, 8 floats per lane.
__global__ void k_sim(const float* __restrict__ fea, const float* __restrict__ invn,
                      const int* __restrict__ row, const int* __restrict__ col,
                      float* __restrict__ sim, float* __restrict__ rs,
                      float* __restrict__ degcnt, int* __restrict__ cnt, int E)
{
    int t = blockIdx.x * blockDim.x + threadIdx.x;
    int e = t >> 3;
    int sub = t & 7;
    if (e >= E) return;
    int r = row[e], c = col[e];
    const float4* fr = (const float4*)(fea + (size_t)r * 64);
    const float4* fc = (const float4*)(fea + (size_t)c * 64);
    float4 a0 = fr[sub * 2], a1 = fr[sub * 2 + 1];
    float4 b0 = fc[sub * 2], b1 = fc[sub * 2 + 1];
    float p = a0.x * b0.x + a0.y * b0.y + a0.z * b0.z + a0.w * b0.w
            + a1.x * b1.x + a1.y * b1.y + a1.z * b1.z + a1.w * b1.w;
    p += __shfl_xor(p, 1);
    p += __shfl_xor(p, 2);
    p += __shfl_xor(p, 4);
    if (sub == 0) {
        float s = p * invn[r] * invn[c];
        if (s < 0.1f) s = 0.0f;
        sim[e] = s;
        if (s > 0.0f) {
            atomicAdd(rs + r, s);
            atomicAdd(degcnt + r, 1.0f);
        }
        if (cnt) atomicAdd(cnt + r, 1);
    }
}

// exclusive prefix sum of cnt[0..n) -> row_ptr[0..n]. single block, 1024 thr.
__global__ void k_scan(const int* __restrict__ cnt, int* __restrict__ row_ptr, int n)
{
    __shared__ int ssum[1025];
    int tid = threadIdx.x;
    int chunk = (n + 1023) / 1024;
    int beg = tid * chunk;
    int end = beg + chunk; if (end > n) end = n; if (beg > n) beg = n;
    int s = 0;
    for (int i = beg; i < end; ++i) s += cnt[i];
    ssum[tid] = s;
    __syncthreads();
    if (tid < 64) {                       // wave 0 scans the 1024 partials
        int lane = tid;
        int t = 0;
#pragma unroll
        for (int i = 0; i < 16; ++i) t += ssum[lane * 16 + i];
        int incl = t;
#pragma unroll
        for (int off = 1; off < 64; off <<= 1) {
            int v = __shfl_up(incl, off);
            if (lane >= off) incl += v;
        }
        int base = incl - t;              // exclusive
#pragma unroll
        for (int i = 0; i < 16; ++i) {
            int tmp = ssum[lane * 16 + i];
            ssum[lane * 16 + i] = base;
            base += tmp;
        }
        if (lane == 63) ssum[1024] = base; // grand total
    }
    __syncthreads();
    int acc = ssum[tid];
    for (int i = beg; i < end; ++i) { row_ptr[i] = acc; acc += cnt[i]; }
    if (tid == 0) row_ptr[n] = ssum[1024];
}

// CSR fill: scatter col into sorted-by-row position; remember pos per edge
__global__ void k_fill(const int* __restrict__ row, const int* __restrict__ col,
                       const int* __restrict__ row_ptr, int* __restrict__ cursor,
                       int* __restrict__ col_s, int* __restrict__ pos, int E)
{
    int e = blockIdx.x * blockDim.x + threadIdx.x;
    if (e >= E) return;
    int r = row[e];
    int pe = row_ptr[r] + atomicAdd(cursor + r, 1);
    col_s[pe] = col[e];
    pos[e] = pe;
}

// per-edge: w = exp(sim / max(rs[row],1e-12)) for kept edges; segW[row] += w.
// writes w into CSR order via pos[e]. writes 0 for dead edges (full coverage).
__global__ void k_wedge(const int* __restrict__ row, const float* __restrict__ sim,
                        const float* __restrict__ rs, float* __restrict__ segW,
                        const int* __restrict__ pos, float* __restrict__ w_s, int E)
{
    int e = blockIdx.x * blockDim.x + threadIdx.x;
    if (e >= E) return;
    float s = sim[e];
    float w = 0.0f;
    if (s > 0.0f) {
        int r = row[e];
        w = expf(s / fmaxf(rs[r], 1e-12f));
        atomicAdd(segW + r, w);
    }
    w_s[pos[e]] = w;
}

// per-node: self-loop weight, dinv = 1/sqrt(deg), selfc = w_self*dinv*dinv
__global__ void k_node(const float* __restrict__ degcnt, const float* __restrict__ segW,
                       float* __restrict__ dinv, float* __restrict__ selfc, int n)
{
    int i = blockIdx.x * blockDim.x + threadIdx.x;
    if (i >= n) return;
    float ws  = expf(1.0f / (degcnt[i] + 1.0f));
    float deg = segW[i] + ws;
    float di  = rsqrtf(fmaxf(deg, 1e-12f));
    dinv[i]  = di;
    selfc[i] = ws * di * di;
}

// dense GEMM out[N,F] = fea[N,64] @ W[64,F].  W + row tile staged in LDS.
template <int F>
__global__ void k_gemm(const float* __restrict__ fea, const float* __restrict__ W,
                       float* __restrict__ out, int n)
{
    constexpr int R = 256 / F;
    __shared__ float sW[64 * F];
    __shared__ float sX[R * 64];
    int tid = threadIdx.x;
    for (int i = tid; i < 64 * F; i += 256) sW[i] = W[i];
    int base = blockIdx.x * R;
    for (int i = tid; i < R * 64; i += 256) {
        int rr = base + i / 64;
        sX[i] = (rr < n) ? fea[(size_t)rr * 64 + (i & 63)] : 0.0f;
    }
    __syncthreads();
    int rl = tid / F, j = tid % F;
    if (rl >= R) return;
    int r = base + rl;
    if (r >= n) return;
    float acc = 0.0f;
#pragma unroll
    for (int k = 0; k < 64; ++k) acc = fmaf(sX[rl * 64 + k], sW[k * F + j], acc);
    out[(size_t)r * F + j] = acc;
}

// live-edge aggregation core: wave loads (col,w) coalesced, ballot-masks live
// edges, extracts 4 at a time, issues independent dinv+feature gathers.
// ACTIVE: lane mask for feature gathers (F<=64). Returns per-lane weighted sum.
template <int F>
__device__ inline float agg_core(const float* __restrict__ h,
                                 const float* __restrict__ dinv,
                                 const int* __restrict__ col_s,
                                 const float* __restrict__ w_s,
                                 int beg, int end, int lane)
{
    float acc = 0.0f;
    bool active = (F == 64) ? true : (lane < F);
    for (int base = beg; base < end; base += 64) {
        int idx = base + lane;
        int cv = 0; float wv = 0.0f;
        if (idx < end) { cv = col_s[idx]; wv = w_s[idx]; }
        unsigned long long m = __ballot(wv > 0.0f);
        while (m) {
            int l0 = __ffsll((unsigned long long)m) - 1; m &= m - 1;
            bool v1 = (m != 0);
            int l1 = v1 ? (__ffsll((unsigned long long)m) - 1) : l0; if (v1) m &= m - 1;
            bool v2 = (m != 0);
            int l2 = v2 ? (__ffsll((unsigned long long)m) - 1) : l0; if (v2) m &= m - 1;
            bool v3 = (m != 0);
            int l3 = v3 ? (__ffsll((unsigned long long)m) - 1) : l0; if (v3) m &= m - 1;

            int   c0 = __shfl(cv, l0); float w0 = __shfl(wv, l0);
            int   c1 = __shfl(cv, l1); float w1 = __shfl(wv, l1); if (!v1) w1 = 0.0f;
            int   c2 = __shfl(cv, l2); float w2 = __shfl(wv, l2); if (!v2) w2 = 0.0f;
            int   c3 = __shfl(cv, l3); float w3 = __shfl(wv, l3); if (!v3) w3 = 0.0f;

            float d0 = dinv[c0], d1 = dinv[c1], d2 = dinv[c2], d3 = dinv[c3];
            float h0 = 0.0f, h1 = 0.0f, h2 = 0.0f, h3 = 0.0f;
            if (active) {
                h0 = h[(size_t)c0 * F + lane];
                h1 = h[(size_t)c1 * F + lane];
                h2 = h[(size_t)c2 * F + lane];
                h3 = h[(size_t)c3 * F + lane];
            }
            acc += w0 * d0 * h0;
            acc += w1 * d1 * h1;
            acc += w2 * d2 * h2;
            acc += w3 * d3 * h3;
        }
    }
    return acc;
}

// layer-1 aggregation + relu + fused inverse-norm of output.
__global__ void k_agg64(const float* __restrict__ h, const float* __restrict__ w_s,
                        const float* __restrict__ dinv, const float* __restrict__ selfc,
                        const float* __restrict__ b, const int* __restrict__ row_ptr,
                        const int* __restrict__ col_s,
                        float* __restrict__ out, float* __restrict__ invn_out, int n)
{
    int gid  = blockIdx.x * blockDim.x + threadIdx.x;
    int wid  = gid >> 6;
    int lane = threadIdx.x & 63;
    if (wid >= n) return;
    int beg = row_ptr[wid], end = row_ptr[wid + 1];
    float acc = agg_core<64>(h, dinv, col_s, w_s, beg, end, lane);
    float v = dinv[wid] * acc + selfc[wid] * h[(size_t)wid * 64 + lane] + b[lane];
    v = fmaxf(v, 0.0f); // relu
    out[(size_t)wid * 64 + lane] = v;
    float s = v * v;
#pragma unroll
    for (int off = 32; off > 0; off >>= 1) s += __shfl_xor(s, off);
    if (lane == 0) invn_out[wid] = 1.0f / fmaxf(sqrtf(s), 1e-12f);
}

// layer-2 aggregation (F=40) fused with bias + log_softmax -> final output.
__global__ void k_agg40_lsm(const float* __restrict__ h2, const float* __restrict__ w_s,
                            const float* __restrict__ dinv, const float* __restrict__ selfc,
                            const float* __restrict__ b, const int* __restrict__ row_ptr,
                            const int* __restrict__ col_s,
                            float* __restrict__ out, int n)
{
    constexpr int F = 40;
    int gid  = blockIdx.x * blockDim.x + threadIdx.x;
    int wid  = gid >> 6;
    int lane = threadIdx.x & 63;
    if (wid >= n) return;
    int beg = row_ptr[wid], end = row_ptr[wid + 1];
    float acc = agg_core<F>(h2, dinv, col_s, w_s, beg, end, lane);
    bool active = (lane < F);
    float v = 0.0f;
    if (active) v = dinv[wid] * acc + selfc[wid] * h2[(size_t)wid * F + lane] + b[lane];
    float m = active ? v : -__builtin_inff();
#pragma unroll
    for (int off = 32; off > 0; off >>= 1) m = fmaxf(m, __shfl_xor(m, off));
    float ex = active ? expf(v - m) : 0.0f;
    float s = ex;
#pragma unroll
    for (int off = 32; off > 0; off >>= 1) s += __shfl_xor(s, off);
    if (active) out[(size_t)wid * F + lane] = v - m - logf(s);
}

extern "C" void kernel_launch(void* const* d_in, const int* in_sizes, int n_in,
                              void* d_out, int out_size, void* d_ws, size_t ws_size,
                              hipStream_t stream)
{
    const float* x  = (const float*)d_in[0];
    const int*   ei = (const int*)d_in[1];
    const float* W1 = (const float*)d_in[2];
    const float* b1 = (const float*)d_in[3];
    const float* W2 = (const float*)d_in[4];
    const float* b2 = (const float*)d_in[5];
    float* out = (float*)d_out;

    const int N = in_sizes[0] / 64;   // 50000
    const int E = in_sizes[1] / 2;    // 800000
    const int* row = ei;
    const int* col = ei + E;

    char* p = (char*)d_ws;
    auto alloc = [&](size_t bytes) -> char* {
        char* r = p; p += (bytes + 255) & ~(size_t)255; return r;
    };
    float* invn_x = (float*)alloc((size_t)N * 4);
    float* invn_h = (float*)alloc((size_t)N * 4);
    float* sim    = (float*)alloc((size_t)E * 4);
    float* rs     = (float*)alloc((size_t)N * 4);
    float* degc   = (float*)alloc((size_t)N * 4);
    float* segW   = (float*)alloc((size_t)N * 4);
    float* dinv   = (float*)alloc((size_t)N * 4);
    float* selfc  = (float*)alloc((size_t)N * 4);
    float* h1     = (float*)alloc((size_t)N * 64 * 4); // x@W1; reused as h2 (N*40)
    float* hrelu  = (float*)alloc((size_t)N * 64 * 4);
    int*   cnt    = (int*)alloc((size_t)N * 4);
    int*   cursor = (int*)alloc((size_t)N * 4);
    int*   rptr   = (int*)alloc((size_t)(N + 1) * 4);
    int*   col_s  = (int*)alloc((size_t)E * 4);
    int*   pos    = (int*)alloc((size_t)E * 4);
    float* w_s    = (float*)alloc((size_t)E * 4);
    float* h2     = h1;

    const int TB = 256;
    int blk_nodeWave = (N * 64 + TB - 1) / TB;
    int blk_edge8    = (E * 8 + TB - 1) / TB;
    int blk_edge     = (E + TB - 1) / TB;
    int blk_node     = (N + TB - 1) / TB;

    // ---- zero accumulators (layer 1 + CSR)
    hipMemsetAsync(rs,     0, (size_t)N * 4, stream);
    hipMemsetAsync(degc,   0, (size_t)N * 4, stream);
    hipMemsetAsync(segW,   0, (size_t)N * 4, stream);
    hipMemsetAsync(cnt,    0, (size_t)N * 4, stream);
    hipMemsetAsync(cursor, 0, (size_t)N * 4, stream);

    // ---- layer 1 attention + CSR build (count fused into sim)
    k_norm<<<blk_nodeWave, TB, 0, stream>>>(x, invn_x, N);
    k_sim<<<blk_edge8, TB, 0, stream>>>(x, invn_x, row, col, sim, rs, degc, cnt, E);
    k_scan<<<1, 1024, 0, stream>>>(cnt, rptr, N);
    k_fill<<<blk_edge, TB, 0, stream>>>(row, col, rptr, cursor, col_s, pos, E);
    k_wedge<<<blk_edge, TB, 0, stream>>>(row, sim, rs, segW, pos, w_s, E);
    k_node<<<blk_node, TB, 0, stream>>>(degc, segW, dinv, selfc, N);

    // ---- layer 1 GCN
    k_gemm<64><<<(N + 3) / 4, TB, 0, stream>>>(x, W1, h1, N);
    k_agg64<<<blk_nodeWave, TB, 0, stream>>>(h1, w_s, dinv, selfc, b1,
                                             rptr, col_s, hrelu, invn_h, N);

    // ---- layer 2 attention
    hipMemsetAsync(rs,   0, (size_t)N * 4, stream);
    hipMemsetAsync(degc, 0, (size_t)N * 4, stream);
    hipMemsetAsync(segW, 0, (size_t)N * 4, stream);
    k_sim<<<blk_edge8, TB, 0, stream>>>(hrelu, invn_h, row, col, sim, rs, degc, (int*)nullptr, E);
    k_wedge<<<blk_edge, TB, 0, stream>>>(row, sim, rs, segW, pos, w_s, E);
    k_node<<<blk_node, TB, 0, stream>>>(degc, segW, dinv, selfc, N);

    // ---- layer 2 GCN + log_softmax
    k_gemm<40><<<(N + 5) / 6, TB, 0, stream>>>(hrelu, W2, h2, N);
    k_agg40_lsm<<<blk_nodeWave, TB, 0, stream>>>(h2, w_s, dinv, selfc, b2,
                                                 rptr, col_s, out, N);
}

// Round 3
// 417.451 us; speedup vs baseline: 1.8228x; 1.2986x over previous
//
#include <hip/hip_runtime.h>
#include <math.h>

// ---------------------------------------------------------------------------
// GuardNet: 2-layer attention-weighted GCN.
// R3: CSR-first; fused per-node attention kernel (sim+threshold+rownorm+exp+
// self-loop+dinv) with wave-local reductions (zero atomics), row features in
// registers, sims stashed in LDS. Pre-normalized feature matrices kill the
// per-edge invn gathers.
// ---------------------------------------------------------------------------

#define ATT_CAP 96   // per-node LDS sim stash; deg>CAP falls back to recompute

// normalize rows: fn[i] = x[i] / max(||x[i]||,1e-12). one wave per node.
__global__ void k_normfn(const float* __restrict__ fea, float* __restrict__ fn, int n)
{
    int gid  = blockIdx.x * blockDim.x + threadIdx.x;
    int wid  = gid >> 6;
    int lane = threadIdx.x & 63;
    if (wid >= n) return;
    float v = fea[(size_t)wid * 64 + lane];
    float s = v * v;
#pragma unroll
    for (int off = 32; off > 0; off >>= 1) s += __shfl_xor(s, off);
    float inv = 1.0f / fmaxf(sqrtf(s), 1e-12f);
    fn[(size_t)wid * 64 + lane] = v * inv;
}

// CSR: count edges per row
__global__ void k_count(const int* __restrict__ row, int* __restrict__ cnt, int E)
{
    int e = blockIdx.x * blockDim.x + threadIdx.x;
    if (e >= E) return;
    atomicAdd(cnt + row[e], 1);
}

// exclusive prefix sum of cnt[0..n) -> row_ptr[0..n]. single block, 1024 thr.
__global__ void k_scan(const int* __restrict__ cnt, int* __restrict__ row_ptr, int n)
{
    __shared__ int ssum[1025];
    int tid = threadIdx.x;
    int chunk = (n + 1023) / 1024;
    int beg = tid * chunk;
    int end = beg + chunk; if (end > n) end = n; if (beg > n) beg = n;
    int s = 0;
    for (int i = beg; i < end; ++i) s += cnt[i];
    ssum[tid] = s;
    __syncthreads();
    if (tid < 64) {
        int lane = tid;
        int t = 0;
#pragma unroll
        for (int i = 0; i < 16; ++i) t += ssum[lane * 16 + i];
        int incl = t;
#pragma unroll
        for (int off = 1; off < 64; off <<= 1) {
            int v = __shfl_up(incl, off);
            if (lane >= off) incl += v;
        }
        int base = incl - t;
#pragma unroll
        for (int i = 0; i < 16; ++i) {
            int tmp = ssum[lane * 16 + i];
            ssum[lane * 16 + i] = base;
            base += tmp;
        }
        if (lane == 63) ssum[1024] = base;
    }
    __syncthreads();
    int acc = ssum[tid];
    for (int i = beg; i < end; ++i) { row_ptr[i] = acc; acc += cnt[i]; }
    if (tid == 0) row_ptr[n] = ssum[1024];
}

// CSR fill: scatter col into sorted-by-row position
__global__ void k_fill(const int* __restrict__ row, const int* __restrict__ col,
                       const int* __restrict__ row_ptr, int* __restrict__ cursor,
                       int* __restrict__ col_s, int E)
{
    int e = blockIdx.x * blockDim.x + threadIdx.x;
    if (e >= E) return;
    int r = row[e];
    int pe = row_ptr[r] + atomicAdd(cursor + r, 1);
    col_s[pe] = col[e];
}

// fused attention: per node (wave), compute edge cosine sims (8 lanes/edge,
// 8 edges/iter), threshold, wave-reduce row-sum & live count, then
// w = exp(sim/rs) per edge (CSR-ordered w_s), wave-reduce segW, and emit
// dinv/selfc. No atomics.
__global__ void k_att(const float* __restrict__ fn,
                      const int* __restrict__ rptr, const int* __restrict__ col_s,
                      float* __restrict__ w_s, float* __restrict__ dinv,
                      float* __restrict__ selfc, int n)
{
    __shared__ float ssim[4][ATT_CAP];
    int wib  = threadIdx.x >> 6;
    int wid  = blockIdx.x * 4 + wib;
    int lane = threadIdx.x & 63;
    if (wid >= n) return;
    int sub = lane & 7;       // lane within 8-lane edge group
    int grp = lane >> 3;      // edge group 0..7
    int beg = rptr[wid], end = rptr[wid + 1];
    int deg_all = end - beg;

    const float4* frp = (const float4*)(fn + (size_t)wid * 64);
    float4 a0 = frp[sub * 2], a1 = frp[sub * 2 + 1];

    float rs_part = 0.0f, dc_part = 0.0f;
    int ngrp = (deg_all + 7) >> 3;
    for (int g = 0; g < ngrp; ++g) {
        int li = g * 8 + grp;
        float s = 0.0f;
        bool valid = (li < deg_all);
        if (valid) {
            int c = col_s[beg + li];
            const float4* fcp = (const float4*)(fn + (size_t)c * 64);
            float4 b0 = fcp[sub * 2], b1 = fcp[sub * 2 + 1];
            float p = a0.x * b0.x + a0.y * b0.y + a0.z * b0.z + a0.w * b0.w
                    + a1.x * b1.x + a1.y * b1.y + a1.z * b1.z + a1.w * b1.w;
            p += __shfl_xor(p, 1);
            p += __shfl_xor(p, 2);
            p += __shfl_xor(p, 4);
            s = (p < 0.1f) ? 0.0f : p;
        }
        if (sub == 0 && valid) {
            if (li < ATT_CAP) ssim[wib][li] = s;
            if (s > 0.0f) { rs_part += s; dc_part += 1.0f; }
        }
    }
#pragma unroll
    for (int off = 32; off > 0; off >>= 1) {
        rs_part += __shfl_xor(rs_part, off);
        dc_part += __shfl_xor(dc_part, off);
    }
    float denom = fmaxf(rs_part, 1e-12f);

    float sw_part = 0.0f;
    for (int g = 0; g < ngrp; ++g) {
        int li = g * 8 + grp;
        bool valid = (li < deg_all);
        float s = 0.0f;
        if (8 * g + 7 < ATT_CAP) {          // wave-uniform fast path
            if (valid && sub == 0) s = ssim[wib][li];
        } else {                             // rare: recompute
            if (valid) {
                int c = col_s[beg + li];
                const float4* fcp = (const float4*)(fn + (size_t)c * 64);
                float4 b0 = fcp[sub * 2], b1 = fcp[sub * 2 + 1];
                float p = a0.x * b0.x + a0.y * b0.y + a0.z * b0.z + a0.w * b0.w
                        + a1.x * b1.x + a1.y * b1.y + a1.z * b1.z + a1.w * b1.w;
                p += __shfl_xor(p, 1);
                p += __shfl_xor(p, 2);
                p += __shfl_xor(p, 4);
                s = (p < 0.1f) ? 0.0f : p;
            }
        }
        if (sub == 0 && valid) {
            float w = 0.0f;
            if (s > 0.0f) { w = expf(s / denom); sw_part += w; }
            w_s[beg + li] = w;
        }
    }
#pragma unroll
    for (int off = 32; off > 0; off >>= 1) sw_part += __shfl_xor(sw_part, off);

    if (lane == 0) {
        float wself = expf(1.0f / (dc_part + 1.0f));
        float D  = sw_part + wself;
        float di = rsqrtf(fmaxf(D, 1e-12f));
        dinv[wid]  = di;
        selfc[wid] = wself * di * di;
    }
}

// dense GEMM out[N,F] = fea[N,64] @ W[64,F].  W + row tile staged in LDS.
template <int F>
__global__ void k_gemm(const float* __restrict__ fea, const float* __restrict__ W,
                       float* __restrict__ out, int n)
{
    constexpr int R = 256 / F;
    __shared__ float sW[64 * F];
    __shared__ float sX[R * 64];
    int tid = threadIdx.x;
    for (int i = tid; i < 64 * F; i += 256) sW[i] = W[i];
    int base = blockIdx.x * R;
    for (int i = tid; i < R * 64; i += 256) {
        int rr = base + i / 64;
        sX[i] = (rr < n) ? fea[(size_t)rr * 64 + (i & 63)] : 0.0f;
    }
    __syncthreads();
    int rl = tid / F, j = tid % F;
    if (rl >= R) return;
    int r = base + rl;
    if (r >= n) return;
    float acc = 0.0f;
#pragma unroll
    for (int k = 0; k < 64; ++k) acc = fmaf(sX[rl * 64 + k], sW[k * F + j], acc);
    out[(size_t)r * F + j] = acc;
}

// live-edge aggregation core: coalesced (col,w) block loads, ballot mask,
// 4-way gather ILP.
template <int F>
__device__ inline float agg_core(const float* __restrict__ h,
                                 const float* __restrict__ dinv,
                                 const int* __restrict__ col_s,
                                 const float* __restrict__ w_s,
                                 int beg, int end, int lane)
{
    float acc = 0.0f;
    bool active = (F == 64) ? true : (lane < F);
    for (int base = beg; base < end; base += 64) {
        int idx = base + lane;
        int cv = 0; float wv = 0.0f;
        if (idx < end) { cv = col_s[idx]; wv = w_s[idx]; }
        unsigned long long m = __ballot(wv > 0.0f);
        while (m) {
            int l0 = __ffsll((unsigned long long)m) - 1; m &= m - 1;
            bool v1 = (m != 0);
            int l1 = v1 ? (__ffsll((unsigned long long)m) - 1) : l0; if (v1) m &= m - 1;
            bool v2 = (m != 0);
            int l2 = v2 ? (__ffsll((unsigned long long)m) - 1) : l0; if (v2) m &= m - 1;
            bool v3 = (m != 0);
            int l3 = v3 ? (__ffsll((unsigned long long)m) - 1) : l0; if (v3) m &= m - 1;

            int   c0 = __shfl(cv, l0); float w0 = __shfl(wv, l0);
            int   c1 = __shfl(cv, l1); float w1 = __shfl(wv, l1); if (!v1) w1 = 0.0f;
            int   c2 = __shfl(cv, l2); float w2 = __shfl(wv, l2); if (!v2) w2 = 0.0f;
            int   c3 = __shfl(cv, l3); float w3 = __shfl(wv, l3); if (!v3) w3 = 0.0f;

            float d0 = dinv[c0], d1 = dinv[c1], d2 = dinv[c2], d3 = dinv[c3];
            float h0 = 0.0f, h1 = 0.0f, h2 = 0.0f, h3 = 0.0f;
            if (active) {
                h0 = h[(size_t)c0 * F + lane];
                h1 = h[(size_t)c1 * F + lane];
                h2 = h[(size_t)c2 * F + lane];
                h3 = h[(size_t)c3 * F + lane];
            }
            acc += w0 * d0 * h0;
            acc += w1 * d1 * h1;
            acc += w2 * d2 * h2;
            acc += w3 * d3 * h3;
        }
    }
    return acc;
}

// layer-1 aggregation + relu; emits hrelu and normalized fnh (for layer-2 att)
__global__ void k_agg64(const float* __restrict__ h, const float* __restrict__ w_s,
                        const float* __restrict__ dinv, const float* __restrict__ selfc,
                        const float* __restrict__ b, const int* __restrict__ row_ptr,
                        const int* __restrict__ col_s,
                        float* __restrict__ out, float* __restrict__ fnh, int n)
{
    int gid  = blockIdx.x * blockDim.x + threadIdx.x;
    int wid  = gid >> 6;
    int lane = threadIdx.x & 63;
    if (wid >= n) return;
    int beg = row_ptr[wid], end = row_ptr[wid + 1];
    float acc = agg_core<64>(h, dinv, col_s, w_s, beg, end, lane);
    float v = dinv[wid] * acc + selfc[wid] * h[(size_t)wid * 64 + lane] + b[lane];
    v = fmaxf(v, 0.0f); // relu
    out[(size_t)wid * 64 + lane] = v;
    float s = v * v;
#pragma unroll
    for (int off = 32; off > 0; off >>= 1) s += __shfl_xor(s, off);
    float inv = 1.0f / fmaxf(sqrtf(s), 1e-12f);
    fnh[(size_t)wid * 64 + lane] = v * inv;
}

// layer-2 aggregation (F=40) fused with bias + log_softmax -> final output.
__global__ void k_agg40_lsm(const float* __restrict__ h2, const float* __restrict__ w_s,
                            const float* __restrict__ dinv, const float* __restrict__ selfc,
                            const float* __restrict__ b, const int* __restrict__ row_ptr,
                            const int* __restrict__ col_s,
                            float* __restrict__ out, int n)
{
    constexpr int F = 40;
    int gid  = blockIdx.x * blockDim.x + threadIdx.x;
    int wid  = gid >> 6;
    int lane = threadIdx.x & 63;
    if (wid >= n) return;
    int beg = row_ptr[wid], end = row_ptr[wid + 1];
    float acc = agg_core<F>(h2, dinv, col_s, w_s, beg, end, lane);
    bool active = (lane < F);
    float v = 0.0f;
    if (active) v = dinv[wid] * acc + selfc[wid] * h2[(size_t)wid * F + lane] + b[lane];
    float m = active ? v : -__builtin_inff();
#pragma unroll
    for (int off = 32; off > 0; off >>= 1) m = fmaxf(m, __shfl_xor(m, off));
    float ex = active ? expf(v - m) : 0.0f;
    float s = ex;
#pragma unroll
    for (int off = 32; off > 0; off >>= 1) s += __shfl_xor(s, off);
    if (active) out[(size_t)wid * F + lane] = v - m - logf(s);
}

extern "C" void kernel_launch(void* const* d_in, const int* in_sizes, int n_in,
                              void* d_out, int out_size, void* d_ws, size_t ws_size,
                              hipStream_t stream)
{
    const float* x  = (const float*)d_in[0];
    const int*   ei = (const int*)d_in[1];
    const float* W1 = (const float*)d_in[2];
    const float* b1 = (const float*)d_in[3];
    const float* W2 = (const float*)d_in[4];
    const float* b2 = (const float*)d_in[5];
    float* out = (float*)d_out;

    const int N = in_sizes[0] / 64;   // 50000
    const int E = in_sizes[1] / 2;    // 800000
    const int* row = ei;
    const int* col = ei + E;

    char* p = (char*)d_ws;
    auto alloc = [&](size_t bytes) -> char* {
        char* r = p; p += (bytes + 255) & ~(size_t)255; return r;
    };
    float* fn     = (float*)alloc((size_t)N * 64 * 4); // normalized x
    float* dinv   = (float*)alloc((size_t)N * 4);
    float* selfc  = (float*)alloc((size_t)N * 4);
    float* h1     = (float*)alloc((size_t)N * 64 * 4); // x@W1; reused as h2 (N*40)
    float* hrelu  = (float*)alloc((size_t)N * 64 * 4);
    float* fnh    = (float*)alloc((size_t)N * 64 * 4); // normalized hrelu
    int*   cnt    = (int*)alloc((size_t)N * 4);
    int*   cursor = (int*)alloc((size_t)N * 4);
    int*   rptr   = (int*)alloc((size_t)(N + 1) * 4);
    int*   col_s  = (int*)alloc((size_t)E * 4);
    float* w_s    = (float*)alloc((size_t)E * 4);
    float* h2     = h1;

    const int TB = 256;
    int blk_nodeWave = (N * 64 + TB - 1) / TB;
    int blk_edge     = (E + TB - 1) / TB;
    int blk_node4    = (N + 3) / 4;

    hipMemsetAsync(cnt,    0, (size_t)N * 4, stream);
    hipMemsetAsync(cursor, 0, (size_t)N * 4, stream);

    // ---- CSR build
    k_count<<<blk_edge, TB, 0, stream>>>(row, cnt, E);
    k_scan<<<1, 1024, 0, stream>>>(cnt, rptr, N);
    k_fill<<<blk_edge, TB, 0, stream>>>(row, col, rptr, cursor, col_s, E);

    // ---- layer 1
    k_normfn<<<blk_nodeWave, TB, 0, stream>>>(x, fn, N);
    k_att<<<blk_node4, TB, 0, stream>>>(fn, rptr, col_s, w_s, dinv, selfc, N);
    k_gemm<64><<<(N + 3) / 4, TB, 0, stream>>>(x, W1, h1, N);
    k_agg64<<<blk_nodeWave, TB, 0, stream>>>(h1, w_s, dinv, selfc, b1,
                                             rptr, col_s, hrelu, fnh, N);

    // ---- layer 2
    k_att<<<blk_node4, TB, 0, stream>>>(fnh, rptr, col_s, w_s, dinv, selfc, N);
    k_gemm<40><<<(N + 5) / 6, TB, 0, stream>>>(hrelu, W2, h2, N);
    k_agg40_lsm<<<blk_nodeWave, TB, 0, stream>>>(h2, w_s, dinv, selfc, b2,
                                                 rptr, col_s, out, N);
}

// Round 4
// 345.575 us; speedup vs baseline: 2.2019x; 1.2080x over previous
//
#include <hip/hip_runtime.h>
#include <math.h>

// ---------------------------------------------------------------------------
// GuardNet: 2-layer attention-weighted GCN.
// R4: replace single-block k_scan (77us, one CU) with 3-kernel hierarchical
// scan (reduce -> scan partials -> scan+add). Rest identical to R3.
// ---------------------------------------------------------------------------

#define ATT_CAP 96   // per-node LDS sim stash; deg>CAP falls back to recompute

// normalize rows: fn[i] = x[i] / max(||x[i]||,1e-12). one wave per node.
__global__ void k_normfn(const float* __restrict__ fea, float* __restrict__ fn, int n)
{
    int gid  = blockIdx.x * blockDim.x + threadIdx.x;
    int wid  = gid >> 6;
    int lane = threadIdx.x & 63;
    if (wid >= n) return;
    float v = fea[(size_t)wid * 64 + lane];
    float s = v * v;
#pragma unroll
    for (int off = 32; off > 0; off >>= 1) s += __shfl_xor(s, off);
    float inv = 1.0f / fmaxf(sqrtf(s), 1e-12f);
    fn[(size_t)wid * 64 + lane] = v * inv;
}

// CSR: count edges per row
__global__ void k_count(const int* __restrict__ row, int* __restrict__ cnt, int E)
{
    int e = blockIdx.x * blockDim.x + threadIdx.x;
    if (e >= E) return;
    atomicAdd(cnt + row[e], 1);
}

// ---- hierarchical exclusive scan of cnt[0..n) -> row_ptr[0..n] --------------
// A: per-block (1024 elems) reduce -> part[b]
__global__ void k_scanA(const int* __restrict__ cnt, int* __restrict__ part, int n)
{
    int tid  = threadIdx.x;
    int lane = tid & 63, wave = tid >> 6;
    int base = blockIdx.x * 1024 + tid * 4;
    int4 c = {0, 0, 0, 0};
    if (base + 3 < n) c = *(const int4*)(cnt + base);
    else {
        if (base + 0 < n) c.x = cnt[base + 0];
        if (base + 1 < n) c.y = cnt[base + 1];
        if (base + 2 < n) c.z = cnt[base + 2];
    }
    int s = c.x + c.y + c.z + c.w;
#pragma unroll
    for (int off = 32; off > 0; off >>= 1) s += __shfl_xor(s, off);
    __shared__ int ws[4];
    if (lane == 0) ws[wave] = s;
    __syncthreads();
    if (tid == 0) part[blockIdx.x] = ws[0] + ws[1] + ws[2] + ws[3];
}

// B: single wave exclusive-scans part[0..nb) in place; writes row_ptr[n]=total
__global__ void k_scanB(int* __restrict__ part, int* __restrict__ row_ptr, int nb, int n)
{
    int lane = threadIdx.x;            // 64 threads
    int K = (nb + 63) / 64;
    int beg = lane * K;
    int s = 0;
    for (int i = 0; i < K; ++i) { int idx = beg + i; if (idx < nb) s += part[idx]; }
    int incl = s;
#pragma unroll
    for (int off = 1; off < 64; off <<= 1) {
        int v = __shfl_up(incl, off);
        if (lane >= off) incl += v;
    }
    int run = incl - s;                // exclusive base for this lane's chunk
    for (int i = 0; i < K; ++i) {
        int idx = beg + i;
        if (idx < nb) { int t = part[idx]; part[idx] = run; run += t; }
    }
    if (lane == 63) row_ptr[n] = incl; // grand total
}

// C: per-block exclusive scan of its 1024 elems + part[b] offset -> row_ptr
__global__ void k_scanC(const int* __restrict__ cnt, const int* __restrict__ part,
                        int* __restrict__ row_ptr, int n)
{
    int tid  = threadIdx.x;
    int lane = tid & 63, wave = tid >> 6;
    int base = blockIdx.x * 1024 + tid * 4;
    int4 c = {0, 0, 0, 0};
    if (base + 3 < n) c = *(const int4*)(cnt + base);
    else {
        if (base + 0 < n) c.x = cnt[base + 0];
        if (base + 1 < n) c.y = cnt[base + 1];
        if (base + 2 < n) c.z = cnt[base + 2];
    }
    int s = c.x + c.y + c.z + c.w;
    int incl = s;
#pragma unroll
    for (int off = 1; off < 64; off <<= 1) {
        int v = __shfl_up(incl, off);
        if (lane >= off) incl += v;
    }
    __shared__ int wsum[4];
    if (lane == 63) wsum[wave] = incl;
    __syncthreads();
    int woff = 0;
    for (int i = 0; i < wave; ++i) woff += wsum[i];
    int excl = part[blockIdx.x] + woff + (incl - s);
    int4 r;
    r.x = excl;
    r.y = r.x + c.x;
    r.z = r.y + c.y;
    r.w = r.z + c.z;
    if (base + 3 < n) *(int4*)(row_ptr + base) = r;
    else {
        if (base + 0 < n) row_ptr[base + 0] = r.x;
        if (base + 1 < n) row_ptr[base + 1] = r.y;
        if (base + 2 < n) row_ptr[base + 2] = r.z;
    }
}

// CSR fill: scatter col into sorted-by-row position
__global__ void k_fill(const int* __restrict__ row, const int* __restrict__ col,
                       const int* __restrict__ row_ptr, int* __restrict__ cursor,
                       int* __restrict__ col_s, int E)
{
    int e = blockIdx.x * blockDim.x + threadIdx.x;
    if (e >= E) return;
    int r = row[e];
    int pe = row_ptr[r] + atomicAdd(cursor + r, 1);
    col_s[pe] = col[e];
}

// fused attention: per node (wave), edge cosine sims (8 lanes/edge), threshold,
// wave-reduced row-sum/live-count, w=exp(sim/rs) (CSR-ordered), segW, dinv/selfc.
__global__ void k_att(const float* __restrict__ fn,
                      const int* __restrict__ rptr, const int* __restrict__ col_s,
                      float* __restrict__ w_s, float* __restrict__ dinv,
                      float* __restrict__ selfc, int n)
{
    __shared__ float ssim[4][ATT_CAP];
    int wib  = threadIdx.x >> 6;
    int wid  = blockIdx.x * 4 + wib;
    int lane = threadIdx.x & 63;
    if (wid >= n) return;
    int sub = lane & 7;
    int grp = lane >> 3;
    int beg = rptr[wid], end = rptr[wid + 1];
    int deg_all = end - beg;

    const float4* frp = (const float4*)(fn + (size_t)wid * 64);
    float4 a0 = frp[sub * 2], a1 = frp[sub * 2 + 1];

    float rs_part = 0.0f, dc_part = 0.0f;
    int ngrp = (deg_all + 7) >> 3;
    for (int g = 0; g < ngrp; ++g) {
        int li = g * 8 + grp;
        float s = 0.0f;
        bool valid = (li < deg_all);
        if (valid) {
            int c = col_s[beg + li];
            const float4* fcp = (const float4*)(fn + (size_t)c * 64);
            float4 b0 = fcp[sub * 2], b1 = fcp[sub * 2 + 1];
            float p = a0.x * b0.x + a0.y * b0.y + a0.z * b0.z + a0.w * b0.w
                    + a1.x * b1.x + a1.y * b1.y + a1.z * b1.z + a1.w * b1.w;
            p += __shfl_xor(p, 1);
            p += __shfl_xor(p, 2);
            p += __shfl_xor(p, 4);
            s = (p < 0.1f) ? 0.0f : p;
        }
        if (sub == 0 && valid) {
            if (li < ATT_CAP) ssim[wib][li] = s;
            if (s > 0.0f) { rs_part += s; dc_part += 1.0f; }
        }
    }
#pragma unroll
    for (int off = 32; off > 0; off >>= 1) {
        rs_part += __shfl_xor(rs_part, off);
        dc_part += __shfl_xor(dc_part, off);
    }
    float denom = fmaxf(rs_part, 1e-12f);

    float sw_part = 0.0f;
    for (int g = 0; g < ngrp; ++g) {
        int li = g * 8 + grp;
        bool valid = (li < deg_all);
        float s = 0.0f;
        if (8 * g + 7 < ATT_CAP) {
            if (valid && sub == 0) s = ssim[wib][li];
        } else {
            if (valid) {
                int c = col_s[beg + li];
                const float4* fcp = (const float4*)(fn + (size_t)c * 64);
                float4 b0 = fcp[sub * 2], b1 = fcp[sub * 2 + 1];
                float p = a0.x * b0.x + a0.y * b0.y + a0.z * b0.z + a0.w * b0.w
                        + a1.x * b1.x + a1.y * b1.y + a1.z * b1.z + a1.w * b1.w;
                p += __shfl_xor(p, 1);
                p += __shfl_xor(p, 2);
                p += __shfl_xor(p, 4);
                s = (p < 0.1f) ? 0.0f : p;
            }
        }
        if (sub == 0 && valid) {
            float w = 0.0f;
            if (s > 0.0f) { w = expf(s / denom); sw_part += w; }
            w_s[beg + li] = w;
        }
    }
#pragma unroll
    for (int off = 32; off > 0; off >>= 1) sw_part += __shfl_xor(sw_part, off);

    if (lane == 0) {
        float wself = expf(1.0f / (dc_part + 1.0f));
        float D  = sw_part + wself;
        float di = rsqrtf(fmaxf(D, 1e-12f));
        dinv[wid]  = di;
        selfc[wid] = wself * di * di;
    }
}

// dense GEMM out[N,F] = fea[N,64] @ W[64,F].  W + row tile staged in LDS.
template <int F>
__global__ void k_gemm(const float* __restrict__ fea, const float* __restrict__ W,
                       float* __restrict__ out, int n)
{
    constexpr int R = 256 / F;
    __shared__ float sW[64 * F];
    __shared__ float sX[R * 64];
    int tid = threadIdx.x;
    for (int i = tid; i < 64 * F; i += 256) sW[i] = W[i];
    int base = blockIdx.x * R;
    for (int i = tid; i < R * 64; i += 256) {
        int rr = base + i / 64;
        sX[i] = (rr < n) ? fea[(size_t)rr * 64 + (i & 63)] : 0.0f;
    }
    __syncthreads();
    int rl = tid / F, j = tid % F;
    if (rl >= R) return;
    int r = base + rl;
    if (r >= n) return;
    float acc = 0.0f;
#pragma unroll
    for (int k = 0; k < 64; ++k) acc = fmaf(sX[rl * 64 + k], sW[k * F + j], acc);
    out[(size_t)r * F + j] = acc;
}

// live-edge aggregation core: coalesced (col,w) block loads, ballot mask,
// 4-way gather ILP.
template <int F>
__device__ inline float agg_core(const float* __restrict__ h,
                                 const float* __restrict__ dinv,
                                 const int* __restrict__ col_s,
                                 const float* __restrict__ w_s,
                                 int beg, int end, int lane)
{
    float acc = 0.0f;
    bool active = (F == 64) ? true : (lane < F);
    for (int base = beg; base < end; base += 64) {
        int idx = base + lane;
        int cv = 0; float wv = 0.0f;
        if (idx < end) { cv = col_s[idx]; wv = w_s[idx]; }
        unsigned long long m = __ballot(wv > 0.0f);
        while (m) {
            int l0 = __ffsll((unsigned long long)m) - 1; m &= m - 1;
            bool v1 = (m != 0);
            int l1 = v1 ? (__ffsll((unsigned long long)m) - 1) : l0; if (v1) m &= m - 1;
            bool v2 = (m != 0);
            int l2 = v2 ? (__ffsll((unsigned long long)m) - 1) : l0; if (v2) m &= m - 1;
            bool v3 = (m != 0);
            int l3 = v3 ? (__ffsll((unsigned long long)m) - 1) : l0; if (v3) m &= m - 1;

            int   c0 = __shfl(cv, l0); float w0 = __shfl(wv, l0);
            int   c1 = __shfl(cv, l1); float w1 = __shfl(wv, l1); if (!v1) w1 = 0.0f;
            int   c2 = __shfl(cv, l2); float w2 = __shfl(wv, l2); if (!v2) w2 = 0.0f;
            int   c3 = __shfl(cv, l3); float w3 = __shfl(wv, l3); if (!v3) w3 = 0.0f;

            float d0 = dinv[c0], d1 = dinv[c1], d2 = dinv[c2], d3 = dinv[c3];
            float h0 = 0.0f, h1 = 0.0f, h2 = 0.0f, h3 = 0.0f;
            if (active) {
                h0 = h[(size_t)c0 * F + lane];
                h1 = h[(size_t)c1 * F + lane];
                h2 = h[(size_t)c2 * F + lane];
                h3 = h[(size_t)c3 * F + lane];
            }
            acc += w0 * d0 * h0;
            acc += w1 * d1 * h1;
            acc += w2 * d2 * h2;
            acc += w3 * d3 * h3;
        }
    }
    return acc;
}

// layer-1 aggregation + relu; emits hrelu and normalized fnh (for layer-2 att)
__global__ void k_agg64(const float* __restrict__ h, const float* __restrict__ w_s,
                        const float* __restrict__ dinv, const float* __restrict__ selfc,
                        const float* __restrict__ b, const int* __restrict__ row_ptr,
                        const int* __restrict__ col_s,
                        float* __restrict__ out, float* __restrict__ fnh, int n)
{
    int gid  = blockIdx.x * blockDim.x + threadIdx.x;
    int wid  = gid >> 6;
    int lane = threadIdx.x & 63;
    if (wid >= n) return;
    int beg = row_ptr[wid], end = row_ptr[wid + 1];
    float acc = agg_core<64>(h, dinv, col_s, w_s, beg, end, lane);
    float v = dinv[wid] * acc + selfc[wid] * h[(size_t)wid * 64 + lane] + b[lane];
    v = fmaxf(v, 0.0f); // relu
    out[(size_t)wid * 64 + lane] = v;
    float s = v * v;
#pragma unroll
    for (int off = 32; off > 0; off >>= 1) s += __shfl_xor(s, off);
    float inv = 1.0f / fmaxf(sqrtf(s), 1e-12f);
    fnh[(size_t)wid * 64 + lane] = v * inv;
}

// layer-2 aggregation (F=40) fused with bias + log_softmax -> final output.
__global__ void k_agg40_lsm(const float* __restrict__ h2, const float* __restrict__ w_s,
                            const float* __restrict__ dinv, const float* __restrict__ selfc,
                            const float* __restrict__ b, const int* __restrict__ row_ptr,
                            const int* __restrict__ col_s,
                            float* __restrict__ out, int n)
{
    constexpr int F = 40;
    int gid  = blockIdx.x * blockDim.x + threadIdx.x;
    int wid  = gid >> 6;
    int lane = threadIdx.x & 63;
    if (wid >= n) return;
    int beg = row_ptr[wid], end = row_ptr[wid + 1];
    float acc = agg_core<F>(h2, dinv, col_s, w_s, beg, end, lane);
    bool active = (lane < F);
    float v = 0.0f;
    if (active) v = dinv[wid] * acc + selfc[wid] * h2[(size_t)wid * F + lane] + b[lane];
    float m = active ? v : -__builtin_inff();
#pragma unroll
    for (int off = 32; off > 0; off >>= 1) m = fmaxf(m, __shfl_xor(m, off));
    float ex = active ? expf(v - m) : 0.0f;
    float s = ex;
#pragma unroll
    for (int off = 32; off > 0; off >>= 1) s += __shfl_xor(s, off);
    if (active) out[(size_t)wid * F + lane] = v - m - logf(s);
}

extern "C" void kernel_launch(void* const* d_in, const int* in_sizes, int n_in,
                              void* d_out, int out_size, void* d_ws, size_t ws_size,
                              hipStream_t stream)
{
    const float* x  = (const float*)d_in[0];
    const int*   ei = (const int*)d_in[1];
    const float* W1 = (const float*)d_in[2];
    const float* b1 = (const float*)d_in[3];
    const float* W2 = (const float*)d_in[4];
    const float* b2 = (const float*)d_in[5];
    float* out = (float*)d_out;

    const int N = in_sizes[0] / 64;   // 50000
    const int E = in_sizes[1] / 2;    // 800000
    const int* row = ei;
    const int* col = ei + E;

    char* p = (char*)d_ws;
    auto alloc = [&](size_t bytes) -> char* {
        char* r = p; p += (bytes + 255) & ~(size_t)255; return r;
    };
    float* fn     = (float*)alloc((size_t)N * 64 * 4); // normalized x
    float* dinv   = (float*)alloc((size_t)N * 4);
    float* selfc  = (float*)alloc((size_t)N * 4);
    float* h1     = (float*)alloc((size_t)N * 64 * 4); // x@W1; reused as h2 (N*40)
    float* hrelu  = (float*)alloc((size_t)N * 64 * 4);
    float* fnh    = (float*)alloc((size_t)N * 64 * 4); // normalized hrelu
    int*   cnt    = (int*)alloc((size_t)N * 4);
    int*   cursor = (int*)alloc((size_t)N * 4);
    int*   rptr   = (int*)alloc((size_t)(N + 1) * 4);
    int*   col_s  = (int*)alloc((size_t)E * 4);
    float* w_s    = (float*)alloc((size_t)E * 4);
    int*   part   = (int*)alloc((size_t)1024 * 4);
    float* h2     = h1;

    const int TB = 256;
    int blk_nodeWave = (N * 64 + TB - 1) / TB;
    int blk_edge     = (E + TB - 1) / TB;
    int blk_node4    = (N + 3) / 4;
    int nb_scan      = (N + 1023) / 1024;

    hipMemsetAsync(cnt,    0, (size_t)N * 4, stream);
    hipMemsetAsync(cursor, 0, (size_t)N * 4, stream);

    // ---- CSR build
    k_count<<<blk_edge, TB, 0, stream>>>(row, cnt, E);
    k_scanA<<<nb_scan, TB, 0, stream>>>(cnt, part, N);
    k_scanB<<<1, 64, 0, stream>>>(part, rptr, nb_scan, N);
    k_scanC<<<nb_scan, TB, 0, stream>>>(cnt, part, rptr, N);
    k_fill<<<blk_edge, TB, 0, stream>>>(row, col, rptr, cursor, col_s, E);

    // ---- layer 1
    k_normfn<<<blk_nodeWave, TB, 0, stream>>>(x, fn, N);
    k_att<<<blk_node4, TB, 0, stream>>>(fn, rptr, col_s, w_s, dinv, selfc, N);
    k_gemm<64><<<(N + 3) / 4, TB, 0, stream>>>(x, W1, h1, N);
    k_agg64<<<blk_nodeWave, TB, 0, stream>>>(h1, w_s, dinv, selfc, b1,
                                             rptr, col_s, hrelu, fnh, N);

    // ---- layer 2
    k_att<<<blk_node4, TB, 0, stream>>>(fnh, rptr, col_s, w_s, dinv, selfc, N);
    k_gemm<40><<<(N + 5) / 6, TB, 0, stream>>>(hrelu, W2, h2, N);
    k_agg40_lsm<<<blk_nodeWave, TB, 0, stream>>>(h2, w_s, dinv, selfc, b2,
                                                 rptr, col_s, out, N);
}

// Round 5
// 341.344 us; speedup vs baseline: 2.2292x; 1.0124x over previous
//
#include <hip/hip_runtime.h>
#include <math.h>

// ---------------------------------------------------------------------------
// GuardNet: 2-layer attention-weighted GCN.
// R5: (a) XCD-partitioned CSR fill (kills 55MB of cross-XCD partial-line
// writeback); (b) k_att emits live-compacted CSR (col_live/w_live/lend) via
// ballot-rank so aggregation loops only over surviving edges with no masking.
// ---------------------------------------------------------------------------

#define ATT_CAP 96   // per-node LDS sim stash; deg>CAP falls back to recompute

// normalize rows: fn[i] = x[i] / max(||x[i]||,1e-12). one wave per node.
__global__ void k_normfn(const float* __restrict__ fea, float* __restrict__ fn, int n)
{
    int gid  = blockIdx.x * blockDim.x + threadIdx.x;
    int wid  = gid >> 6;
    int lane = threadIdx.x & 63;
    if (wid >= n) return;
    float v = fea[(size_t)wid * 64 + lane];
    float s = v * v;
#pragma unroll
    for (int off = 32; off > 0; off >>= 1) s += __shfl_xor(s, off);
    float inv = 1.0f / fmaxf(sqrtf(s), 1e-12f);
    fn[(size_t)wid * 64 + lane] = v * inv;
}

// CSR: count edges per row
__global__ void k_count(const int* __restrict__ row, int* __restrict__ cnt, int E)
{
    int e = blockIdx.x * blockDim.x + threadIdx.x;
    if (e >= E) return;
    atomicAdd(cnt + row[e], 1);
}

// ---- hierarchical exclusive scan of cnt[0..n) -> row_ptr[0..n] --------------
__global__ void k_scanA(const int* __restrict__ cnt, int* __restrict__ part, int n)
{
    int tid  = threadIdx.x;
    int lane = tid & 63, wave = tid >> 6;
    int base = blockIdx.x * 1024 + tid * 4;
    int4 c = {0, 0, 0, 0};
    if (base + 3 < n) c = *(const int4*)(cnt + base);
    else {
        if (base + 0 < n) c.x = cnt[base + 0];
        if (base + 1 < n) c.y = cnt[base + 1];
        if (base + 2 < n) c.z = cnt[base + 2];
    }
    int s = c.x + c.y + c.z + c.w;
#pragma unroll
    for (int off = 32; off > 0; off >>= 1) s += __shfl_xor(s, off);
    __shared__ int ws[4];
    if (lane == 0) ws[wave] = s;
    __syncthreads();
    if (tid == 0) part[blockIdx.x] = ws[0] + ws[1] + ws[2] + ws[3];
}

__global__ void k_scanB(int* __restrict__ part, int* __restrict__ row_ptr, int nb, int n)
{
    int lane = threadIdx.x;            // 64 threads
    int K = (nb + 63) / 64;
    int beg = lane * K;
    int s = 0;
    for (int i = 0; i < K; ++i) { int idx = beg + i; if (idx < nb) s += part[idx]; }
    int incl = s;
#pragma unroll
    for (int off = 1; off < 64; off <<= 1) {
        int v = __shfl_up(incl, off);
        if (lane >= off) incl += v;
    }
    int run = incl - s;
    for (int i = 0; i < K; ++i) {
        int idx = beg + i;
        if (idx < nb) { int t = part[idx]; part[idx] = run; run += t; }
    }
    if (lane == 63) row_ptr[n] = incl;
}

__global__ void k_scanC(const int* __restrict__ cnt, const int* __restrict__ part,
                        int* __restrict__ row_ptr, int n)
{
    int tid  = threadIdx.x;
    int lane = tid & 63, wave = tid >> 6;
    int base = blockIdx.x * 1024 + tid * 4;
    int4 c = {0, 0, 0, 0};
    if (base + 3 < n) c = *(const int4*)(cnt + base);
    else {
        if (base + 0 < n) c.x = cnt[base + 0];
        if (base + 1 < n) c.y = cnt[base + 1];
        if (base + 2 < n) c.z = cnt[base + 2];
    }
    int s = c.x + c.y + c.z + c.w;
    int incl = s;
#pragma unroll
    for (int off = 1; off < 64; off <<= 1) {
        int v = __shfl_up(incl, off);
        if (lane >= off) incl += v;
    }
    __shared__ int wsum[4];
    if (lane == 63) wsum[wave] = incl;
    __syncthreads();
    int woff = 0;
    for (int i = 0; i < wave; ++i) woff += wsum[i];
    int excl = part[blockIdx.x] + woff + (incl - s);
    int4 r;
    r.x = excl;
    r.y = r.x + c.x;
    r.z = r.y + c.y;
    r.w = r.z + c.z;
    if (base + 3 < n) *(int4*)(row_ptr + base) = r;
    else {
        if (base + 0 < n) row_ptr[base + 0] = r.x;
        if (base + 1 < n) row_ptr[base + 1] = r.y;
        if (base + 2 < n) row_ptr[base + 2] = r.z;
    }
}

// XCD-partitioned CSR fill: block's XCD slice (blockIdx&7) owns rows
// [xcd*N/8,(xcd+1)*N/8); scattered col_s writes for those rows then stay in
// one XCD's L2 and coalesce before writeback. Row/col streams are LLC-served.
__global__ void k_fill_p(const int* __restrict__ row, const int* __restrict__ col,
                         const int* __restrict__ rptr, int* __restrict__ cursor,
                         int* __restrict__ col_s, int E, int N)
{
    int xcd    = blockIdx.x & 7;
    int slice  = blockIdx.x >> 3;
    int nslice = gridDim.x >> 3;
    int lo = (int)(((long long)N * xcd) >> 3);
    int hi = (int)(((long long)N * (xcd + 1)) >> 3);
    int ebeg = (int)((long long)E * slice / nslice);
    int eend = (int)((long long)E * (slice + 1) / nslice);
    for (int e = ebeg + threadIdx.x; e < eend; e += blockDim.x) {
        int r = row[e];
        if (r >= lo && r < hi) {
            int pe = rptr[r] + atomicAdd(cursor + r, 1);
            col_s[pe] = col[e];
        }
    }
}

// fused attention: per node (wave): pass1 = edge cosine sims (8 lanes/edge)
// stashed in LDS + wave-reduced row-sum; pass2 = w=exp(sim/rs), ballot-rank
// compaction into (col_live,w_live), segW reduce, lend/dinv/selfc. No atomics.
__global__ void k_att(const float* __restrict__ fn,
                      const int* __restrict__ rptr, const int* __restrict__ col_s,
                      int* __restrict__ col_live, float* __restrict__ w_live,
                      int* __restrict__ lend, float* __restrict__ dinv,
                      float* __restrict__ selfc, int n)
{
    __shared__ float ssim[4][ATT_CAP];
    __shared__ int   scol[4][ATT_CAP];
    int wib  = threadIdx.x >> 6;
    int wid  = blockIdx.x * 4 + wib;
    int lane = threadIdx.x & 63;
    if (wid >= n) return;
    int sub = lane & 7;
    int grp = lane >> 3;
    int beg = rptr[wid], end = rptr[wid + 1];
    int deg_all = end - beg;

    const float4* frp = (const float4*)(fn + (size_t)wid * 64);
    float4 a0 = frp[sub * 2], a1 = frp[sub * 2 + 1];

    // pass 1: sims + row-sum
    float rs_part = 0.0f;
    int ngrp = (deg_all + 7) >> 3;
    for (int g = 0; g < ngrp; ++g) {
        int li = g * 8 + grp;
        float s = 0.0f; int c = 0;
        bool valid = (li < deg_all);
        if (valid) {
            c = col_s[beg + li];
            const float4* fcp = (const float4*)(fn + (size_t)c * 64);
            float4 b0 = fcp[sub * 2], b1 = fcp[sub * 2 + 1];
            float p = a0.x * b0.x + a0.y * b0.y + a0.z * b0.z + a0.w * b0.w
                    + a1.x * b1.x + a1.y * b1.y + a1.z * b1.z + a1.w * b1.w;
            p += __shfl_xor(p, 1);
            p += __shfl_xor(p, 2);
            p += __shfl_xor(p, 4);
            s = (p < 0.1f) ? 0.0f : p;
        }
        if (sub == 0 && valid) {
            if (li < ATT_CAP) { ssim[wib][li] = s; scol[wib][li] = c; }
            if (s > 0.0f) rs_part += s;
        }
    }
#pragma unroll
    for (int off = 32; off > 0; off >>= 1) rs_part += __shfl_xor(rs_part, off);
    float denom = fmaxf(rs_part, 1e-12f);

    // pass 2: weights + live compaction (lane = edge index within 64-chunk)
    int   nlive = 0;
    float sw_lane = 0.0f;
    for (int base = 0; base < deg_all; base += 64) {
        int li = base + lane;
        bool valid = (li < deg_all);
        float s = 0.0f; int c = 0;
        if (valid) {
            if (li < ATT_CAP) { s = ssim[wib][li]; c = scol[wib][li]; }
            else {                           // astronomically rare: per-lane dot
                c = col_s[beg + li];
                const float* fr = fn + (size_t)wid * 64;
                const float* fc = fn + (size_t)c * 64;
                float p = 0.0f;
                for (int k = 0; k < 64; ++k) p += fr[k] * fc[k];
                s = (p < 0.1f) ? 0.0f : p;
            }
        }
        float w = (valid && s > 0.0f) ? expf(s / denom) : 0.0f;
        unsigned long long M = __ballot(w > 0.0f);
        int rank = __popcll(M & ((1ull << lane) - 1ull));
        if (w > 0.0f) {
            col_live[beg + nlive + rank] = c;
            w_live[beg + nlive + rank]   = w;
            sw_lane += w;
        }
        nlive += __popcll(M);
    }
#pragma unroll
    for (int off = 32; off > 0; off >>= 1) sw_lane += __shfl_xor(sw_lane, off);

    if (lane == 0) {
        float wself = expf(1.0f / ((float)nlive + 1.0f));
        float D  = sw_lane + wself;
        float di = rsqrtf(fmaxf(D, 1e-12f));
        lend[wid]  = beg + nlive;
        dinv[wid]  = di;
        selfc[wid] = wself * di * di;
    }
}

// dense GEMM out[N,F] = fea[N,64] @ W[64,F].  W + row tile staged in LDS.
template <int F>
__global__ void k_gemm(const float* __restrict__ fea, const float* __restrict__ W,
                       float* __restrict__ out, int n)
{
    constexpr int R = 256 / F;
    __shared__ float sW[64 * F];
    __shared__ float sX[R * 64];
    int tid = threadIdx.x;
    for (int i = tid; i < 64 * F; i += 256) sW[i] = W[i];
    int base = blockIdx.x * R;
    for (int i = tid; i < R * 64; i += 256) {
        int rr = base + i / 64;
        sX[i] = (rr < n) ? fea[(size_t)rr * 64 + (i & 63)] : 0.0f;
    }
    __syncthreads();
    int rl = tid / F, j = tid % F;
    if (rl >= R) return;
    int r = base + rl;
    if (r >= n) return;
    float acc = 0.0f;
#pragma unroll
    for (int k = 0; k < 64; ++k) acc = fmaf(sX[rl * 64 + k], sW[k * F + j], acc);
    out[(size_t)r * F + j] = acc;
}

// live-edge aggregation: all edges in [beg,lend) are live. Coalesced (col,w)
// chunk load, 4-way broadcast+gather ILP, no masking (dead lanes carry w=0).
template <int F>
__device__ inline float agg_core_live(const float* __restrict__ h,
                                      const float* __restrict__ dinv,
                                      const int* __restrict__ col_live,
                                      const float* __restrict__ w_live,
                                      int beg, int lend_, int lane)
{
    float acc = 0.0f;
    bool active = (F == 64) ? true : (lane < F);
    for (int base = beg; base < lend_; base += 64) {
        int idx = base + lane;
        int cv = 0; float wv = 0.0f;
        if (idx < lend_) { cv = col_live[idx]; wv = w_live[idx]; }
        int cnt = lend_ - base; if (cnt > 64) cnt = 64;
        for (int j = 0; j < cnt; j += 4) {
            int   c0 = __shfl(cv, j);     float w0 = __shfl(wv, j);
            int   c1 = __shfl(cv, j + 1); float w1 = __shfl(wv, j + 1);
            int   c2 = __shfl(cv, j + 2); float w2 = __shfl(wv, j + 2);
            int   c3 = __shfl(cv, j + 3); float w3 = __shfl(wv, j + 3);
            float d0 = dinv[c0], d1 = dinv[c1], d2 = dinv[c2], d3 = dinv[c3];
            float h0 = 0.0f, h1 = 0.0f, h2 = 0.0f, h3 = 0.0f;
            if (active) {
                h0 = h[(size_t)c0 * F + lane];
                h1 = h[(size_t)c1 * F + lane];
                h2 = h[(size_t)c2 * F + lane];
                h3 = h[(size_t)c3 * F + lane];
            }
            acc += w0 * d0 * h0;
            acc += w1 * d1 * h1;
            acc += w2 * d2 * h2;
            acc += w3 * d3 * h3;
        }
    }
    return acc;
}

// layer-1 aggregation + relu; emits hrelu and normalized fnh (for layer-2 att)
__global__ void k_agg64(const float* __restrict__ h, const float* __restrict__ w_live,
                        const int* __restrict__ col_live,
                        const float* __restrict__ dinv, const float* __restrict__ selfc,
                        const float* __restrict__ b, const int* __restrict__ row_ptr,
                        const int* __restrict__ lend,
                        float* __restrict__ out, float* __restrict__ fnh, int n)
{
    int gid  = blockIdx.x * blockDim.x + threadIdx.x;
    int wid  = gid >> 6;
    int lane = threadIdx.x & 63;
    if (wid >= n) return;
    int beg = row_ptr[wid], le = lend[wid];
    float acc = agg_core_live<64>(h, dinv, col_live, w_live, beg, le, lane);
    float v = dinv[wid] * acc + selfc[wid] * h[(size_t)wid * 64 + lane] + b[lane];
    v = fmaxf(v, 0.0f); // relu
    out[(size_t)wid * 64 + lane] = v;
    float s = v * v;
#pragma unroll
    for (int off = 32; off > 0; off >>= 1) s += __shfl_xor(s, off);
    float inv = 1.0f / fmaxf(sqrtf(s), 1e-12f);
    fnh[(size_t)wid * 64 + lane] = v * inv;
}

// layer-2 aggregation (F=40) fused with bias + log_softmax -> final output.
__global__ void k_agg40_lsm(const float* __restrict__ h2, const float* __restrict__ w_live,
                            const int* __restrict__ col_live,
                            const float* __restrict__ dinv, const float* __restrict__ selfc,
                            const float* __restrict__ b, const int* __restrict__ row_ptr,
                            const int* __restrict__ lend,
                            float* __restrict__ out, int n)
{
    constexpr int F = 40;
    int gid  = blockIdx.x * blockDim.x + threadIdx.x;
    int wid  = gid >> 6;
    int lane = threadIdx.x & 63;
    if (wid >= n) return;
    int beg = row_ptr[wid], le = lend[wid];
    float acc = agg_core_live<F>(h2, dinv, col_live, w_live, beg, le, lane);
    bool active = (lane < F);
    float v = 0.0f;
    if (active) v = dinv[wid] * acc + selfc[wid] * h2[(size_t)wid * F + lane] + b[lane];
    float m = active ? v : -__builtin_inff();
#pragma unroll
    for (int off = 32; off > 0; off >>= 1) m = fmaxf(m, __shfl_xor(m, off));
    float ex = active ? expf(v - m) : 0.0f;
    float s = ex;
#pragma unroll
    for (int off = 32; off > 0; off >>= 1) s += __shfl_xor(s, off);
    if (active) out[(size_t)wid * F + lane] = v - m - logf(s);
}

extern "C" void kernel_launch(void* const* d_in, const int* in_sizes, int n_in,
                              void* d_out, int out_size, void* d_ws, size_t ws_size,
                              hipStream_t stream)
{
    const float* x  = (const float*)d_in[0];
    const int*   ei = (const int*)d_in[1];
    const float* W1 = (const float*)d_in[2];
    const float* b1 = (const float*)d_in[3];
    const float* W2 = (const float*)d_in[4];
    const float* b2 = (const float*)d_in[5];
    float* out = (float*)d_out;

    const int N = in_sizes[0] / 64;   // 50000
    const int E = in_sizes[1] / 2;    // 800000
    const int* row = ei;
    const int* col = ei + E;

    char* p = (char*)d_ws;
    auto alloc = [&](size_t bytes) -> char* {
        char* r = p; p += (bytes + 255) & ~(size_t)255; return r;
    };
    float* fn     = (float*)alloc((size_t)N * 64 * 4); // normalized x
    float* dinv   = (float*)alloc((size_t)N * 4);
    float* selfc  = (float*)alloc((size_t)N * 4);
    float* h1     = (float*)alloc((size_t)N * 64 * 4); // x@W1; reused as h2 (N*40)
    float* hrelu  = (float*)alloc((size_t)N * 64 * 4);
    float* fnh    = (float*)alloc((size_t)N * 64 * 4); // normalized hrelu
    int*   cnt    = (int*)alloc((size_t)N * 4);
    int*   cursor = (int*)alloc((size_t)N * 4);
    int*   rptr   = (int*)alloc((size_t)(N + 1) * 4);
    int*   lendv  = (int*)alloc((size_t)N * 4);
    int*   col_s  = (int*)alloc((size_t)E * 4);
    int*   col_lv = (int*)alloc((size_t)E * 4);
    float* w_lv   = (float*)alloc((size_t)E * 4);
    int*   part   = (int*)alloc((size_t)1024 * 4);
    float* h2     = h1;

    const int TB = 256;
    int blk_nodeWave = (N * 64 + TB - 1) / TB;
    int blk_edge     = (E + TB - 1) / TB;
    int blk_node4    = (N + 3) / 4;
    int nb_scan      = (N + 1023) / 1024;

    hipMemsetAsync(cnt,    0, (size_t)N * 4, stream);
    hipMemsetAsync(cursor, 0, (size_t)N * 4, stream);

    // ---- CSR build
    k_count<<<blk_edge, TB, 0, stream>>>(row, cnt, E);
    k_scanA<<<nb_scan, TB, 0, stream>>>(cnt, part, N);
    k_scanB<<<1, 64, 0, stream>>>(part, rptr, nb_scan, N);
    k_scanC<<<nb_scan, TB, 0, stream>>>(cnt, part, rptr, N);
    k_fill_p<<<8 * 104, TB, 0, stream>>>(row, col, rptr, cursor, col_s, E, N);

    // ---- layer 1
    k_normfn<<<blk_nodeWave, TB, 0, stream>>>(x, fn, N);
    k_att<<<blk_node4, TB, 0, stream>>>(fn, rptr, col_s, col_lv, w_lv, lendv,
                                        dinv, selfc, N);
    k_gemm<64><<<(N + 3) / 4, TB, 0, stream>>>(x, W1, h1, N);
    k_agg64<<<blk_nodeWave, TB, 0, stream>>>(h1, w_lv, col_lv, dinv, selfc, b1,
                                             rptr, lendv, hrelu, fnh, N);

    // ---- layer 2
    k_att<<<blk_node4, TB, 0, stream>>>(fnh, rptr, col_s, col_lv, w_lv, lendv,
                                        dinv, selfc, N);
    k_gemm<40><<<(N + 5) / 6, TB, 0, stream>>>(hrelu, W2, h2, N);
    k_agg40_lsm<<<blk_nodeWave, TB, 0, stream>>>(h2, w_lv, col_lv, dinv, selfc, b2,
                                                 rptr, lendv, out, N);
}